// Round 13
// baseline (194.012 us; speedup 1.0000x reference)
//
#include <hip/hip_runtime.h>
#include <hip/hip_bf16.h>
#include <math.h>

typedef __attribute__((ext_vector_type(8))) short bfrag;   // 8 bf16 (16B)
typedef __attribute__((ext_vector_type(4))) float ffrag;   // mfma acc
typedef __attribute__((ext_vector_type(4))) float f4v;
typedef __attribute__((ext_vector_type(2))) float f2v;
typedef __attribute__((ext_vector_type(2))) unsigned u2v;

#define C3 1536   // 3*H*D
#define PS 24     // P LDS row stride (shorts)
#define VS 136    // vt row stride (shorts); padding kept (harmless)

__device__ __forceinline__ unsigned short f2bf(float f) {
    unsigned u = __float_as_uint(f);
    return (unsigned short)((u + 0x7FFFu + ((u >> 16) & 1u)) >> 16);  // RNE
}
__device__ __forceinline__ float bf2f(unsigned short u) {
    return __uint_as_float((unsigned)u << 16);
}

// sum over the 16 lanes of a DPP row
__device__ __forceinline__ float row16_sum(float x) {
    int v;
    v = __builtin_amdgcn_update_dpp(0, __float_as_int(x), 0xB1, 0xF, 0xF, true);
    x += __int_as_float(v);
    v = __builtin_amdgcn_update_dpp(0, __float_as_int(x), 0x4E, 0xF, 0xF, true);
    x += __int_as_float(v);
    v = __builtin_amdgcn_update_dpp(0, __float_as_int(x), 0x124, 0xF, 0xF, true);
    x += __int_as_float(v);
    v = __builtin_amdgcn_update_dpp(0, __float_as_int(x), 0x128, 0xF, 0xF, true);
    x += __int_as_float(v);
    return x;
}

// ---------- kernel 1: cqkv bf16 (cq pre-scaled 1/8, blocks 0..1535)
//            + pq'/pk bf16 rows + pv B-frag table + gbtab (blocks 1536..1631) ----------
__global__ __launch_bounds__(256) void precompute_kernel(
    const float* __restrict__ char_emb, const float* __restrict__ Wc, const float* __restrict__ bc,
    const float* __restrict__ Wp, const float* __restrict__ bp,
    const float* __restrict__ gamma, const float* __restrict__ beta,
    unsigned short* __restrict__ cqkv, unsigned short* __restrict__ pbf,
    unsigned short* __restrict__ pvb, float* __restrict__ gbtab)
{
    const int b = blockIdx.x;
    const int t = threadIdx.x;
    if (b < 1536) {
        const int mt = b / 6;
        const int nt = b - mt * 6;
        const int m0 = mt * 8;
        const int c = nt * 256 + t;
        const float qs = (c < 512) ? 0.125f : 1.f;   // bake 1/TEMP into q
        const float bias = bc[c];
        float acc[8];
        #pragma unroll
        for (int r = 0; r < 8; ++r) acc[r] = bias;
        #pragma unroll 16
        for (int dd = 0; dd < 64; ++dd) {
            const float wv = Wc[dd * C3 + c];
            #pragma unroll
            for (int r = 0; r < 8; ++r)
                acc[r] = fmaf(char_emb[(m0 + r) * 64 + dd], wv, acc[r]);  // uniform -> s_load
        }
        #pragma unroll
        for (int r = 0; r < 8; ++r)
            cqkv[(size_t)(m0 + r) * C3 + c] = f2bf(acc[r] * qs);
    } else {                             // one (l, cc) pair per block
        const int e = b - 1536;
        const int l = e / 6;
        const int cc = e - l * 6;
        if (b == 1536 && t < 64) {       // gbtab[n][0..3]=gamma dt, [4..7]=beta dt
            #pragma unroll
            for (int dt = 0; dt < 4; ++dt) {
                gbtab[t * 8 + dt]     = gamma[dt * 16 + t];
                gbtab[t * 8 + 4 + dt] = beta[dt * 16 + t];
            }
        }
        __shared__ float spos[64];
        if (t < 64) {
            const int f = t & 31;
            const float inv = exp2f(-(float)f * 0.41524101186092034f);
            const float ph = (float)l * inv;
            spos[t] = (t < 32) ? cosf(ph) : sinf(ph);
        }
        __syncthreads();
        const int c = t + cc * 256;
        float acc = bp[c];
        #pragma unroll
        for (int dd = 0; dd < 64; ++dd)
            acc = fmaf(spos[dd], Wp[dd * C3 + c], acc);
        if (c < 1024) {                  // pq'/pk rows: [(s*8+h)][l][d]
            const float qs = (c < 512) ? 0.125f : 1.f;
            pbf[(c >> 6) * 1024 + l * 64 + (c & 63)] = f2bf(acc * qs);
        } else {                         // pv B-frag table: [h][dt][q2][n][j], k=q2*8+j=l, col=n=d&15
            const int h = (c >> 6) & 7, d = c & 63;
            pvb[((h * 4 + (d >> 4)) * 2 + (l >> 3)) * 128 + (d & 15) * 8 + (l & 7)] = f2bf(acc);
        }
    }
}

// ---------- kernel 1b: word-independent S-phase tables (MFMA form) ----------
//   cps[h][v][l] = cq'[v,h]·pk[l,h] + ck[v,h]·pq'[l,h]  (K=128)
//   blocks 0..255: one h (b>>5), 64 v's (4 waves x 16); wave = 16v x 16l tile, 4 MFMA.
//   blocks 256..263: pqk[h][r][c] = pq'[r,h]·pk[c,h], 1 entry/thread (was 1 serial
//   block doing 8/thread — sat on the graph critical path).
__global__ __launch_bounds__(256) void cp_kernel(
    const unsigned short* __restrict__ cqkv, const unsigned short* __restrict__ pbf,
    float* __restrict__ cps, float* __restrict__ pqk)
{
    const int b = blockIdx.x;
    const int t = threadIdx.x;
    if (b < 256) {
        const int lane = t & 63, wid = t >> 6;
        const int quad = lane >> 4, n = lane & 15;
        const int h = b >> 5;
        const int v0 = (b & 31) * 64 + wid * 16;
        const unsigned short* arow = cqkv + (size_t)(v0 + n) * C3 + h * 64;  // A row v0+n: cq' then ck(+512)
        const unsigned short* pk = pbf + (8 + h) * 1024 + n * 64;            // B col n, k<64
        const unsigned short* pq = pbf + h * 1024 + n * 64;                  // B col n, k>=64
        ffrag acc = {0.f, 0.f, 0.f, 0.f};
        #pragma unroll
        for (int s = 0; s < 2; ++s) {
            const bfrag aF = *(const bfrag*)(arow + s * 32 + quad * 8);
            const bfrag bF = *(const bfrag*)(pk + s * 32 + quad * 8);
            acc = __builtin_amdgcn_mfma_f32_16x16x32_bf16(aF, bF, acc, 0, 0, 0);
        }
        #pragma unroll
        for (int s = 0; s < 2; ++s) {
            const bfrag aF = *(const bfrag*)(arow + 512 + s * 32 + quad * 8);
            const bfrag bF = *(const bfrag*)(pq + s * 32 + quad * 8);
            acc = __builtin_amdgcn_mfma_f32_16x16x32_bf16(aF, bF, acc, 0, 0, 0);
        }
        #pragma unroll
        for (int r = 0; r < 4; ++r)   // C/D: col=lane&15, row=quad*4+r
            cps[((size_t)h * 2048 + v0 + quad * 4 + r) * 16 + n] = acc[r];
    } else {
        const int e = (b - 256) * 256 + t;   // 0..2047, one entry per thread
        const int h = e >> 8, r = (e >> 4) & 15, c = e & 15;
        const unsigned short* pq = pbf + h * 1024 + r * 64;
        const unsigned short* pk = pbf + (8 + h) * 1024 + c * 64;
        float s = 0.f;
        #pragma unroll
        for (int c8 = 0; c8 < 8; ++c8) {
            const bfrag a = *(const bfrag*)(pq + c8 * 8);
            const bfrag bb = *(const bfrag*)(pk + c8 * 8);
            #pragma unroll
            for (int j = 0; j < 8; ++j)
                s += bf2f((unsigned short)a[j]) * bf2f((unsigned short)bb[j]);
        }
        pqk[e] = s;
    }
}

// ---------- kernel 2: attention, head-partitioned (R11: FETCH 20x down, L2-affinity
//   confirmed). R12 verdict: issue-bound (~350 VALU inst/wave; no pipe saturated).
//   This round: S^T softmax path — merge of two HW-validated pieces:
//   (a) R9's swapped-operand S^T + f4v bias C-init (correctness validated);
//   (b) R8's sP write->b128 read transpose (fast; avoids R9's serial bpermutes).
//   Lane(quad,n) elem r = S[q=n][k=quad*4+r]: bias = 2 aligned f4v loads (kills
//   4 cps gathers + 4 pqk scalars + 4 rc shfls); exp+mask -> 2 cvt_pk + 1
//   ds_write_b64 (kills 4 f2bf + 3 LDS writes). Read side unchanged.
//   bounds (256,7): validated no-spill for this 32-arch body (R12). ----------
__global__ __launch_bounds__(256, 7) void attn_kernel(
    const unsigned short* __restrict__ cqkv,
    const unsigned short* __restrict__ pvb, const int* __restrict__ char_code,
    const float* __restrict__ gbtab,
    const float* __restrict__ cps, const float* __restrict__ pqk,
    float* __restrict__ pooled)
{
    // per-WAVE scratch (wave-local RAW/WAR handled by lgkmcnt, no barriers needed)
    __shared__ __attribute__((aligned(16))) unsigned short sVt[4 * 8 * VS];   // cv tile, per-wave
    __shared__ __attribute__((aligned(16))) unsigned short sP[4 * 16 * PS];   // P tile, per-wave

    const int t = threadIdx.x;
    const int lane = t & 63;
    const int wid = t >> 6;
    const int h = blockIdx.x & 7;                    // head = XCD affinity
    const int w = (blockIdx.x >> 3) * 4 + wid;       // word: 4 per block, 1 per wave
    const int quad = lane >> 4;
    const int n = lane & 15;
    const int q2 = quad & 1;

    const int code = char_code[w * 16 + n];
    const bool kvalid = (code != 0);
    const unsigned long long msk = __ballot(kvalid);
    const int nv = __popcll(msk & 0xFFFFull);

    // per-elem k-char (= quad*4+r) validity — masks exp (P^T cols) and LN pool rows
    float mrow[4];
    #pragma unroll
    for (int r = 0; r < 4; ++r)
        mrow[r] = ((msk >> (quad * 4 + r)) & 1ull) ? 1.f : 0.f;

    const f4v g4 = *(const f4v*)(gbtab + n * 8);
    const f4v b4 = *(const f4v*)(gbtab + n * 8 + 4);

    unsigned short* vt = sVt + wid * 8 * VS;
    unsigned short* pt = sP + wid * 16 * PS;

    bfrag onesf;
    #pragma unroll
    for (int j = 0; j < 8; ++j) onesf[j] = (short)0x3F80;

    // ---- stage cv (raw bf16 copy, swizzled B-frag layout) for this head ----
    const unsigned short* cvp = cqkv + (size_t)code * C3 + 1024 + h * 64;
    #pragma unroll
    for (int cc = 0; cc < 2; ++cc) {
        const int d8 = quad + cc * 4;
        const bfrag cv = *(const bfrag*)(cvp + d8 * 8);
        #pragma unroll
        for (int j = 0; j < 8; ++j) {
            const int d = d8 * 8 + j;
            const int e = ((d >> 4) * 2 + (n >> 3)) * VS
                        + ((d & 15) ^ ((n >> 3) << 2)) * 8 + (n & 7);
            vt[e] = (unsigned short)cv[j];
        }
    }

    // ---- S^T: C-init = cps[h][code(n)][4q..4q+3] + pqk[h][n][4q..4q+3] (f4v),
    //      swapped-operand MFMA -> lane elem r = S[q=n][k=quad*4+r] ----
    const f4v c4 = *(const f4v*)(cps + (size_t)h * 32768 + code * 16 + quad * 4);
    const f4v p4 = *(const f4v*)(pqk + h * 256 + n * 16 + quad * 4);
    ffrag accST;
    #pragma unroll
    for (int r = 0; r < 4; ++r) accST[r] = c4[r] + p4[r];
    const unsigned short* cbase = cqkv + (size_t)code * C3 + h * 64;
    #pragma unroll
    for (int cc = 0; cc < 2; ++cc) {
        const int off = quad * 8 + cc * 32;
        const bfrag cqF = *(const bfrag*)(cbase + off);
        const bfrag ckF = *(const bfrag*)(cbase + 512 + off);
        accST = __builtin_amdgcn_mfma_f32_16x16x32_bf16(ckF, cqF, accST, 0, 0, 0);
    }

    // ---- P^T = exp(S^T) masked by k-validity; pack 2x cvt_pk; ONE ds_write_b64
    //      pt[q][k]: addr = n*PS + quad*4 (4 consecutive k-shorts, 8B aligned) ----
    const float pr0 = mrow[0] * __expf(accST[0]);
    const float pr1 = mrow[1] * __expf(accST[1]);
    const float pr2 = mrow[2] * __expf(accST[2]);
    const float pr3 = mrow[3] * __expf(accST[3]);
    unsigned d0, d1;
    asm("v_cvt_pk_bf16_f32 %0, %1, %2" : "=v"(d0) : "v"(pr0), "v"(pr1));
    asm("v_cvt_pk_bf16_f32 %0, %1, %2" : "=v"(d1) : "v"(pr2), "v"(pr3));
    u2v pw; pw[0] = d0; pw[1] = d1;
    *(u2v*)(pt + n * PS + quad * 4) = pw;

    // ---- O = P·cv (LDS) + P·pv (direct B-frag) ; sm via ones-MFMA ; LN + pool ----
    bfrag ap;
    #pragma unroll
    for (int j = 0; j < 8; ++j) ap[j] = 0;
    if (quad < 2) ap = *(const bfrag*)(pt + n * PS + quad * 8);
    ffrag accO[4];
    #pragma unroll
    for (int dt = 0; dt < 4; ++dt) { ffrag z = {0.f,0.f,0.f,0.f}; accO[dt] = z; }
    #pragma unroll
    for (int dt = 0; dt < 4; ++dt) {
        const bfrag bcv = *(const bfrag*)(vt + (dt * 2 + q2) * VS + (n ^ (q2 << 2)) * 8);
        accO[dt] = __builtin_amdgcn_mfma_f32_16x16x32_bf16(ap, bcv, accO[dt], 0, 0, 0);
        const bfrag bpv = *(const bfrag*)(pvb + ((h * 4 + dt) * 2 + q2) * 128 + n * 8);
        accO[dt] = __builtin_amdgcn_mfma_f32_16x16x32_bf16(ap, bpv, accO[dt], 0, 0, 0);
    }
    ffrag accE = {0.f, 0.f, 0.f, 0.f};
    accE = __builtin_amdgcn_mfma_f32_16x16x32_bf16(ap, onesf, accE, 0, 0, 0);

    float ps1[4], ps2[4];
    #pragma unroll
    for (int r = 0; r < 4; ++r) {
        ps1[r] = accO[0][r] + accO[1][r] + accO[2][r] + accO[3][r];
        ps2[r] = accO[0][r]*accO[0][r] + accO[1][r]*accO[1][r]
               + accO[2][r]*accO[2][r] + accO[3][r]*accO[3][r];
        ps1[r] = row16_sum(ps1[r]);
        ps2[r] = row16_sum(ps2[r]);
    }
    float pool[4] = {0.f, 0.f, 0.f, 0.f};
    #pragma unroll
    for (int r = 0; r < 4; ++r) {
        const float mu   = ps1[r] * 0.015625f;
        const float var  = fmaxf(ps2[r] * 0.015625f - mu * mu, 0.f);
        const float rstd = rsqrtf(var + accE[r] * accE[r] * 1e-5f);
        #pragma unroll
        for (int dt = 0; dt < 4; ++dt)
            pool[dt] += mrow[r] * fmaf((accO[dt][r] - mu) * rstd, g4[dt], b4[dt]);
    }
    #pragma unroll
    for (int xm = 16; xm <= 32; xm <<= 1) {
        #pragma unroll
        for (int dt = 0; dt < 4; ++dt) pool[dt] += __shfl_xor(pool[dt], xm);
    }
    if (quad == 0) {
        const float invnv = 1.f / (float)nv;
        f4v res;
        #pragma unroll
        for (int dt = 0; dt < 4; ++dt) res[dt] = pool[dt] * invnv;
        *(f4v*)(pooled + (size_t)w * 512 + h * 64 + n * 4) = res;   // [w][h][n][dt]
    }
}

// ---------- kernel 3: per-name word gather + per-word MLP + average ----------
//   lane = d (0..63). Per gathered word: pl[hh] = pooled[wc][hh*64 + (d&15)*4 + (d>>4)],
//   hid c=relu(pl·W1[:,c]+b1[c]), out o += hid·W2[c,o]; avg over words; +b2 (linear).
__global__ __launch_bounds__(256) void name_mlp_avg_kernel(
    const float* __restrict__ pooled, const int* __restrict__ word_code,
    const int* __restrict__ n_words,
    const float* __restrict__ W1, const float* __restrict__ b1,
    const float* __restrict__ W2, const float* __restrict__ b2,
    float* __restrict__ out)
{
    __shared__ float sWb[280];   // W1@0 [8][16], b1@128, W2@144 [16][8], b2@272
    const int t = threadIdx.x;
    const int lane = t & 63;
    const int nm = blockIdx.x * 4 + (t >> 6);

    if (t < 128) { sWb[t] = W1[t]; sWb[144 + t] = W2[t]; }
    else if (t < 144) sWb[t] = b1[t - 128];
    else if (t < 152) sWb[272 + (t - 144)] = b2[t - 144];
    __syncthreads();

    int part = 0;
    for (int i = lane; i < nm; i += 64) part += n_words[i];
    #pragma unroll
    for (int xm = 1; xm <= 32; xm <<= 1) part += __shfl_xor(part, xm);
    const int off = part;
    const int cnt = n_words[nm];

    const int pidx = (lane & 15) * 4 + (lane >> 4);   // pooled sub-index for this d
    float a[8];
    #pragma unroll
    for (int o = 0; o < 8; ++o) a[o] = 0.f;

    for (int r = 0; r < cnt; ++r) {
        const int wc = word_code[off + r];
        const float* pr = pooled + (size_t)wc * 512 + pidx;
        float pl[8];
        #pragma unroll
        for (int hh = 0; hh < 8; ++hh) pl[hh] = pr[hh * 64];
        #pragma unroll
        for (int c = 0; c < 16; ++c) {
            float hs = sWb[128 + c];
            #pragma unroll
            for (int hh = 0; hh < 8; ++hh) hs = fmaf(pl[hh], sWb[hh * 16 + c], hs);
            hs = fmaxf(hs, 0.f);
            #pragma unroll
            for (int o = 0; o < 8; ++o) a[o] = fmaf(hs, sWb[144 + c * 8 + o], a[o]);
        }
    }
    const float inv = 1.f / (float)cnt;
    f4v r0, r1;
    #pragma unroll
    for (int o = 0; o < 4; ++o) { r0[o] = a[o] * inv + sWb[272 + o]; }
    #pragma unroll
    for (int o = 0; o < 4; ++o) { r1[o] = a[4 + o] * inv + sWb[276 + o]; }
    *(f4v*)(out + (size_t)nm * 512 + lane * 8) = r0;
    *(f4v*)(out + (size_t)nm * 512 + lane * 8 + 4) = r1;
}

extern "C" void kernel_launch(void* const* d_in, const int* in_sizes, int n_in,
                              void* d_out, int out_size, void* d_ws, size_t ws_size,
                              hipStream_t stream) {
    (void)in_sizes; (void)n_in; (void)out_size; (void)ws_size;
    const float* char_emb = (const float*)d_in[0];
    const float* Wc    = (const float*)d_in[1];
    const float* bc    = (const float*)d_in[2];
    const float* Wp    = (const float*)d_in[3];
    const float* bp    = (const float*)d_in[4];
    const float* gamma = (const float*)d_in[5];
    const float* beta  = (const float*)d_in[6];
    const float* W1    = (const float*)d_in[7];
    const float* b1    = (const float*)d_in[8];
    const float* W2    = (const float*)d_in[9];
    const float* b2    = (const float*)d_in[10];
    const int* char_code = (const int*)d_in[11];
    const int* word_code = (const int*)d_in[12];
    const int* n_words   = (const int*)d_in[13];   // harness passes ints as int32

    char* ws = (char*)d_ws;
    unsigned short* cqkv = (unsigned short*)ws;                 //  6,291,456 B
    unsigned short* pbf  = (unsigned short*)(ws + 6291456);     //     32,768 B
    unsigned short* pvb  = (unsigned short*)(ws + 6324224);     //     16,384 B
    float* pooled = (float*)(ws + 6340608);                     // 16,777,216 B
    float* gbtab = (float*)(ws + 23117824);                     //      2,048 B
    float* cps   = (float*)(ws + 23119872);                     //  1,048,576 B
    float* pqk   = (float*)(ws + 24168448);                     //      8,192 B
    float* out = (float*)d_out;

    precompute_kernel<<<1632, 256, 0, stream>>>(char_emb, Wc, bc, Wp, bp, gamma, beta,
                                                cqkv, pbf, pvb, gbtab);
    cp_kernel<<<264, 256, 0, stream>>>(cqkv, pbf, cps, pqk);
    attn_kernel<<<16384, 256, 0, stream>>>(cqkv, pvb, char_code, gbtab, cps, pqk, pooled);
    name_mlp_avg_kernel<<<512, 256, 0, stream>>>(pooled, word_code, n_words,
                                                 W1, b1, W2, b2, out);
}

// Round 15
// 191.544 us; speedup vs baseline: 1.0129x; 1.0129x over previous
//
#include <hip/hip_runtime.h>
#include <hip/hip_bf16.h>
#include <math.h>

typedef __attribute__((ext_vector_type(8))) short bfrag;   // 8 bf16 (16B)
typedef __attribute__((ext_vector_type(4))) float ffrag;   // mfma acc
typedef __attribute__((ext_vector_type(4))) float f4v;
typedef __attribute__((ext_vector_type(2))) float f2v;

#define C3 1536   // 3*H*D
#define PS 24     // P LDS row stride (shorts)
#define VS 136    // vt row stride (shorts)

__device__ __forceinline__ unsigned short f2bf(float f) {
    unsigned u = __float_as_uint(f);
    return (unsigned short)((u + 0x7FFFu + ((u >> 16) & 1u)) >> 16);  // RNE
}
__device__ __forceinline__ float bf2f(unsigned short u) {
    return __uint_as_float((unsigned)u << 16);
}

// sum over the 16 lanes of a DPP row
__device__ __forceinline__ float row16_sum(float x) {
    int v;
    v = __builtin_amdgcn_update_dpp(0, __float_as_int(x), 0xB1, 0xF, 0xF, true);
    x += __int_as_float(v);
    v = __builtin_amdgcn_update_dpp(0, __float_as_int(x), 0x4E, 0xF, 0xF, true);
    x += __int_as_float(v);
    v = __builtin_amdgcn_update_dpp(0, __float_as_int(x), 0x124, 0xF, 0xF, true);
    x += __int_as_float(v);
    v = __builtin_amdgcn_update_dpp(0, __float_as_int(x), 0x128, 0xF, 0xF, true);
    x += __int_as_float(v);
    return x;
}

// ---------- kernel 1: cqkv bf16 (cq pre-scaled 1/8, blocks 0..1535)
//            + pq'/pk bf16 rows + pv B-frag table + gbtab (blocks 1536..1631) ----------
__global__ __launch_bounds__(256) void precompute_kernel(
    const float* __restrict__ char_emb, const float* __restrict__ Wc, const float* __restrict__ bc,
    const float* __restrict__ Wp, const float* __restrict__ bp,
    const float* __restrict__ gamma, const float* __restrict__ beta,
    unsigned short* __restrict__ cqkv, unsigned short* __restrict__ pbf,
    unsigned short* __restrict__ pvb, float* __restrict__ gbtab)
{
    const int b = blockIdx.x;
    const int t = threadIdx.x;
    if (b < 1536) {
        const int mt = b / 6;
        const int nt = b - mt * 6;
        const int m0 = mt * 8;
        const int c = nt * 256 + t;
        const float qs = (c < 512) ? 0.125f : 1.f;   // bake 1/TEMP into q
        const float bias = bc[c];
        float acc[8];
        #pragma unroll
        for (int r = 0; r < 8; ++r) acc[r] = bias;
        #pragma unroll 16
        for (int dd = 0; dd < 64; ++dd) {
            const float wv = Wc[dd * C3 + c];
            #pragma unroll
            for (int r = 0; r < 8; ++r)
                acc[r] = fmaf(char_emb[(m0 + r) * 64 + dd], wv, acc[r]);  // uniform -> s_load
        }
        #pragma unroll
        for (int r = 0; r < 8; ++r)
            cqkv[(size_t)(m0 + r) * C3 + c] = f2bf(acc[r] * qs);
    } else {                             // one (l, cc) pair per block
        const int e = b - 1536;
        const int l = e / 6;
        const int cc = e - l * 6;
        if (b == 1536 && t < 64) {       // gbtab[n][0..3]=gamma dt, [4..7]=beta dt
            #pragma unroll
            for (int dt = 0; dt < 4; ++dt) {
                gbtab[t * 8 + dt]     = gamma[dt * 16 + t];
                gbtab[t * 8 + 4 + dt] = beta[dt * 16 + t];
            }
        }
        __shared__ float spos[64];
        if (t < 64) {
            const int f = t & 31;
            const float inv = exp2f(-(float)f * 0.41524101186092034f);
            const float ph = (float)l * inv;
            spos[t] = (t < 32) ? cosf(ph) : sinf(ph);
        }
        __syncthreads();
        const int c = t + cc * 256;
        float acc = bp[c];
        #pragma unroll
        for (int dd = 0; dd < 64; ++dd)
            acc = fmaf(spos[dd], Wp[dd * C3 + c], acc);
        if (c < 1024) {                  // pq'/pk rows: [(s*8+h)][l][d]
            const float qs = (c < 512) ? 0.125f : 1.f;
            pbf[(c >> 6) * 1024 + l * 64 + (c & 63)] = f2bf(acc * qs);
        } else {                         // pv B-frag table: [h][dt][q2][n][j], k=q2*8+j=l, col=n=d&15
            const int h = (c >> 6) & 7, d = c & 63;
            pvb[((h * 4 + (d >> 4)) * 2 + (l >> 3)) * 128 + (d & 15) * 8 + (l & 7)] = f2bf(acc);
        }
    }
}

// ---------- kernel 1b: word-independent S-phase tables (MFMA form) ----------
//   cps[h][v][l] = cq'[v,h]·pk[l,h] + ck[v,h]·pq'[l,h]  (K=128)
//   blocks 0..255: one h (b>>5), 64 v's (4 waves x 16); wave = 16v x 16l tile, 4 MFMA.
//   blocks 256..263: pqk[h][r][c] = pq'[r,h]·pk[c,h], 1 entry/thread.
__global__ __launch_bounds__(256) void cp_kernel(
    const unsigned short* __restrict__ cqkv, const unsigned short* __restrict__ pbf,
    float* __restrict__ cps, float* __restrict__ pqk)
{
    const int b = blockIdx.x;
    const int t = threadIdx.x;
    if (b < 256) {
        const int lane = t & 63, wid = t >> 6;
        const int quad = lane >> 4, n = lane & 15;
        const int h = b >> 5;
        const int v0 = (b & 31) * 64 + wid * 16;
        const unsigned short* arow = cqkv + (size_t)(v0 + n) * C3 + h * 64;  // A row v0+n: cq' then ck(+512)
        const unsigned short* pk = pbf + (8 + h) * 1024 + n * 64;            // B col n, k<64
        const unsigned short* pq = pbf + h * 1024 + n * 64;                  // B col n, k>=64
        ffrag acc = {0.f, 0.f, 0.f, 0.f};
        #pragma unroll
        for (int s = 0; s < 2; ++s) {
            const bfrag aF = *(const bfrag*)(arow + s * 32 + quad * 8);
            const bfrag bF = *(const bfrag*)(pk + s * 32 + quad * 8);
            acc = __builtin_amdgcn_mfma_f32_16x16x32_bf16(aF, bF, acc, 0, 0, 0);
        }
        #pragma unroll
        for (int s = 0; s < 2; ++s) {
            const bfrag aF = *(const bfrag*)(arow + 512 + s * 32 + quad * 8);
            const bfrag bF = *(const bfrag*)(pq + s * 32 + quad * 8);
            acc = __builtin_amdgcn_mfma_f32_16x16x32_bf16(aF, bF, acc, 0, 0, 0);
        }
        #pragma unroll
        for (int r = 0; r < 4; ++r)   // C/D: col=lane&15, row=quad*4+r
            cps[((size_t)h * 2048 + v0 + quad * 4 + r) * 16 + n] = acc[r];
    } else {
        const int e = (b - 256) * 256 + t;   // 0..2047, one entry per thread
        const int h = e >> 8, r = (e >> 4) & 15, c = e & 15;
        const unsigned short* pq = pbf + h * 1024 + r * 64;
        const unsigned short* pk = pbf + (8 + h) * 1024 + c * 64;
        float s = 0.f;
        #pragma unroll
        for (int c8 = 0; c8 < 8; ++c8) {
            const bfrag a = *(const bfrag*)(pq + c8 * 8);
            const bfrag bb = *(const bfrag*)(pk + c8 * 8);
            #pragma unroll
            for (int j = 0; j < 8; ++j)
                s += bf2f((unsigned short)a[j]) * bf2f((unsigned short)bb[j]);
        }
        pqk[e] = s;
    }
}

// ---------- kernel 2: attention, head-partitioned — R12-VALIDATED BODY (byte-exact
//   revert; R13 S^T-bias and R14 tr_read both regressed/failed — the sP write ->
//   b128 read round-trip is the best-measured transpose schedule on this HW).
//   h = bid & 7 -> per-XCD working set = one head (FETCH 115.6 -> 5.7 MB, R11).
//   bounds (256,7): validated no-spill for this 32-arch body (R12). ----------
__global__ __launch_bounds__(256, 7) void attn_kernel(
    const unsigned short* __restrict__ cqkv,
    const unsigned short* __restrict__ pvb, const int* __restrict__ char_code,
    const float* __restrict__ gbtab,
    const float* __restrict__ cps, const float* __restrict__ pqk,
    float* __restrict__ pooled)
{
    // per-WAVE scratch (wave-local RAW/WAR handled by lgkmcnt, no barriers needed)
    __shared__ __attribute__((aligned(16))) unsigned short sVt[4 * 8 * VS];   // cv tile, per-wave
    __shared__ __attribute__((aligned(16))) unsigned short sP[4 * 16 * PS];   // P tile, per-wave

    const int t = threadIdx.x;
    const int lane = t & 63;
    const int wid = t >> 6;
    const int h = blockIdx.x & 7;                    // head = XCD affinity
    const int w = (blockIdx.x >> 3) * 4 + wid;       // word: 4 per block, 1 per wave
    const int quad = lane >> 4;
    const int n = lane & 15;
    const int q2 = quad & 1;

    const int code = char_code[w * 16 + n];
    const bool kvalid = (code != 0);
    const unsigned long long msk = __ballot(kvalid);
    const int nv = __popcll(msk & 0xFFFFull);

    // codes of the 4 S-rows this lane owns (row = quad*4+rr)
    int rc[4];
    #pragma unroll
    for (int rr = 0; rr < 4; ++rr) rc[rr] = __shfl(code, quad * 4 + rr);

    const f4v g4 = *(const f4v*)(gbtab + n * 8);
    const f4v b4 = *(const f4v*)(gbtab + n * 8 + 4);

    unsigned short* vt = sVt + wid * 8 * VS;
    unsigned short* pt = sP + wid * 16 * PS;

    bfrag onesf;
    #pragma unroll
    for (int j = 0; j < 8; ++j) onesf[j] = (short)0x3F80;

    // ---- stage cv (raw bf16 copy, swizzled B-frag layout) for this head ----
    const unsigned short* cvp = cqkv + (size_t)code * C3 + 1024 + h * 64;
    #pragma unroll
    for (int cc = 0; cc < 2; ++cc) {
        const int d8 = quad + cc * 4;
        const bfrag cv = *(const bfrag*)(cvp + d8 * 8);
        #pragma unroll
        for (int j = 0; j < 8; ++j) {
            const int d = d8 * 8 + j;
            const int e = ((d >> 4) * 2 + (n >> 3)) * VS
                        + ((d & 15) ^ ((n >> 3) << 2)) * 8 + (n & 7);
            vt[e] = (unsigned short)cv[j];
        }
    }

    // ---- S: bias = cp[h][rowcode][n] + posqk[h][row][n], then cq'·ck MFMA ----
    const float* cph = cps + (size_t)h * 32768;   // [2048][16]
    const float* pqh = pqk + h * 256;             // [16][16]
    ffrag accS;
    #pragma unroll
    for (int rr = 0; rr < 4; ++rr)
        accS[rr] = cph[rc[rr] * 16 + n] + pqh[(quad * 4 + rr) * 16 + n];
    const unsigned short* cbase = cqkv + (size_t)code * C3 + h * 64;
    #pragma unroll
    for (int cc = 0; cc < 2; ++cc) {
        const int off = quad * 8 + cc * 32;
        const bfrag cqF = *(const bfrag*)(cbase + off);
        const bfrag ckF = *(const bfrag*)(cbase + 512 + off);
        accS = __builtin_amdgcn_mfma_f32_16x16x32_bf16(cqF, ckF, accS, 0, 0, 0);
    }

    // ---- softmax (no max-sub; logits tiny), UNNORMALIZED P ----
    #pragma unroll
    for (int r = 0; r < 4; ++r) {
        const float pr = kvalid ? __expf(accS[r]) : 0.f;
        pt[(quad * 4 + r) * PS + n] = f2bf(pr);
    }

    // ---- O = P·cv (LDS) + P·pv (direct B-frag) ; sm via ones-MFMA ; LN + pool ----
    bfrag ap;
    #pragma unroll
    for (int j = 0; j < 8; ++j) ap[j] = 0;
    if (quad < 2) ap = *(const bfrag*)(pt + n * PS + quad * 8);
    ffrag accO[4];
    #pragma unroll
    for (int dt = 0; dt < 4; ++dt) { ffrag z = {0.f,0.f,0.f,0.f}; accO[dt] = z; }
    #pragma unroll
    for (int dt = 0; dt < 4; ++dt) {
        const bfrag bcv = *(const bfrag*)(vt + (dt * 2 + q2) * VS + (n ^ (q2 << 2)) * 8);
        accO[dt] = __builtin_amdgcn_mfma_f32_16x16x32_bf16(ap, bcv, accO[dt], 0, 0, 0);
        const bfrag bpv = *(const bfrag*)(pvb + ((h * 4 + dt) * 2 + q2) * 128 + n * 8);
        accO[dt] = __builtin_amdgcn_mfma_f32_16x16x32_bf16(ap, bpv, accO[dt], 0, 0, 0);
    }
    ffrag accE = {0.f, 0.f, 0.f, 0.f};
    accE = __builtin_amdgcn_mfma_f32_16x16x32_bf16(ap, onesf, accE, 0, 0, 0);

    float ps1[4], ps2[4];
    #pragma unroll
    for (int r = 0; r < 4; ++r) {
        ps1[r] = accO[0][r] + accO[1][r] + accO[2][r] + accO[3][r];
        ps2[r] = accO[0][r]*accO[0][r] + accO[1][r]*accO[1][r]
               + accO[2][r]*accO[2][r] + accO[3][r]*accO[3][r];
        ps1[r] = row16_sum(ps1[r]);
        ps2[r] = row16_sum(ps2[r]);
    }
    float pool[4] = {0.f, 0.f, 0.f, 0.f};
    #pragma unroll
    for (int r = 0; r < 4; ++r) {
        const float mu   = ps1[r] * 0.015625f;
        const float var  = fmaxf(ps2[r] * 0.015625f - mu * mu, 0.f);
        const float rstd = rsqrtf(var + accE[r] * accE[r] * 1e-5f);
        const float iv = ((msk >> (quad * 4 + r)) & 1ull) ? 1.f : 0.f;
        #pragma unroll
        for (int dt = 0; dt < 4; ++dt)
            pool[dt] += iv * fmaf((accO[dt][r] - mu) * rstd, g4[dt], b4[dt]);
    }
    #pragma unroll
    for (int xm = 16; xm <= 32; xm <<= 1) {
        #pragma unroll
        for (int dt = 0; dt < 4; ++dt) pool[dt] += __shfl_xor(pool[dt], xm);
    }
    if (quad == 0) {
        const float invnv = 1.f / (float)nv;
        f4v res;
        #pragma unroll
        for (int dt = 0; dt < 4; ++dt) res[dt] = pool[dt] * invnv;
        *(f4v*)(pooled + (size_t)w * 512 + h * 64 + n * 4) = res;   // [w][h][n][dt]
    }
}

// ---------- kernel 3: per-name word gather + per-word MLP + average ----------
//   lane = d (0..63). Per gathered word: pl[hh] = pooled[wc][hh*64 + (d&15)*4 + (d>>4)],
//   hid c=relu(pl·W1[:,c]+b1[c]), out o += hid·W2[c,o]; avg over words; +b2 (linear).
__global__ __launch_bounds__(256) void name_mlp_avg_kernel(
    const float* __restrict__ pooled, const int* __restrict__ word_code,
    const int* __restrict__ n_words,
    const float* __restrict__ W1, const float* __restrict__ b1,
    const float* __restrict__ W2, const float* __restrict__ b2,
    float* __restrict__ out)
{
    __shared__ float sWb[280];   // W1@0 [8][16], b1@128, W2@144 [16][8], b2@272
    const int t = threadIdx.x;
    const int lane = t & 63;
    const int nm = blockIdx.x * 4 + (t >> 6);

    if (t < 128) { sWb[t] = W1[t]; sWb[144 + t] = W2[t]; }
    else if (t < 144) sWb[t] = b1[t - 128];
    else if (t < 152) sWb[272 + (t - 144)] = b2[t - 144];
    __syncthreads();

    int part = 0;
    for (int i = lane; i < nm; i += 64) part += n_words[i];
    #pragma unroll
    for (int xm = 1; xm <= 32; xm <<= 1) part += __shfl_xor(part, xm);
    const int off = part;
    const int cnt = n_words[nm];

    const int pidx = (lane & 15) * 4 + (lane >> 4);   // pooled sub-index for this d
    float a[8];
    #pragma unroll
    for (int o = 0; o < 8; ++o) a[o] = 0.f;

    for (int r = 0; r < cnt; ++r) {
        const int wc = word_code[off + r];
        const float* pr = pooled + (size_t)wc * 512 + pidx;
        float pl[8];
        #pragma unroll
        for (int hh = 0; hh < 8; ++hh) pl[hh] = pr[hh * 64];
        #pragma unroll
        for (int c = 0; c < 16; ++c) {
            float hs = sWb[128 + c];
            #pragma unroll
            for (int hh = 0; hh < 8; ++hh) hs = fmaf(pl[hh], sWb[hh * 16 + c], hs);
            hs = fmaxf(hs, 0.f);
            #pragma unroll
            for (int o = 0; o < 8; ++o) a[o] = fmaf(hs, sWb[144 + c * 8 + o], a[o]);
        }
    }
    const float inv = 1.f / (float)cnt;
    f4v r0, r1;
    #pragma unroll
    for (int o = 0; o < 4; ++o) { r0[o] = a[o] * inv + sWb[272 + o]; }
    #pragma unroll
    for (int o = 0; o < 4; ++o) { r1[o] = a[4 + o] * inv + sWb[276 + o]; }
    *(f4v*)(out + (size_t)nm * 512 + lane * 8) = r0;
    *(f4v*)(out + (size_t)nm * 512 + lane * 8 + 4) = r1;
}

extern "C" void kernel_launch(void* const* d_in, const int* in_sizes, int n_in,
                              void* d_out, int out_size, void* d_ws, size_t ws_size,
                              hipStream_t stream) {
    (void)in_sizes; (void)n_in; (void)out_size; (void)ws_size;
    const float* char_emb = (const float*)d_in[0];
    const float* Wc    = (const float*)d_in[1];
    const float* bc    = (const float*)d_in[2];
    const float* Wp    = (const float*)d_in[3];
    const float* bp    = (const float*)d_in[4];
    const float* gamma = (const float*)d_in[5];
    const float* beta  = (const float*)d_in[6];
    const float* W1    = (const float*)d_in[7];
    const float* b1    = (const float*)d_in[8];
    const float* W2    = (const float*)d_in[9];
    const float* b2    = (const float*)d_in[10];
    const int* char_code = (const int*)d_in[11];
    const int* word_code = (const int*)d_in[12];
    const int* n_words   = (const int*)d_in[13];   // harness passes ints as int32

    char* ws = (char*)d_ws;
    unsigned short* cqkv = (unsigned short*)ws;                 //  6,291,456 B
    unsigned short* pbf  = (unsigned short*)(ws + 6291456);     //     32,768 B
    unsigned short* pvb  = (unsigned short*)(ws + 6324224);     //     16,384 B
    float* pooled = (float*)(ws + 6340608);                     // 16,777,216 B
    float* gbtab = (float*)(ws + 23117824);                     //      2,048 B
    float* cps   = (float*)(ws + 23119872);                     //  1,048,576 B
    float* pqk   = (float*)(ws + 24168448);                     //      8,192 B
    float* out = (float*)d_out;

    precompute_kernel<<<1632, 256, 0, stream>>>(char_emb, Wc, bc, Wp, bp, gamma, beta,
                                                cqkv, pbf, pvb, gbtab);
    cp_kernel<<<264, 256, 0, stream>>>(cqkv, pbf, cps, pqk);
    attn_kernel<<<16384, 256, 0, stream>>>(cqkv, pvb, char_code, gbtab, cps, pqk, pooled);
    name_mlp_avg_kernel<<<512, 256, 0, stream>>>(pooled, word_code, n_words,
                                                 W1, b1, W2, b2, out);
}